// Round 1
// baseline (25.709 us; speedup 1.0000x reference)
//
#include <hip/hip_runtime.h>
#include <math.h>

#define H_OUT 225
#define W_OUT 400
#define NPIX (H_OUT * W_OUT)      // 90000
#define NBOX 128
#define BS   256
#define NB   ((NPIX + BS - 1) / BS)   // 352 blocks

// EPS64 = np.finfo(np.float64).eps
#define EPS64F 2.2204460492503131e-16f

__global__ __launch_bounds__(BS) void segloss_main(
    const float* __restrict__ boxes,   // (128,4) [u1,v1,u2,v2]
    const float* __restrict__ pred,    // (1,2,225,400)
    float* __restrict__ part)          // 3*NB partials: [sfg | sbg | snp]
{
    __shared__ int   sbx[NBOX], sby[NBOX], sr[NBOX], scol[NBOX];
    __shared__ float s2s[NBOX];        // 2*sigma^2

    const int t = threadIdx.x;
    if (t < NBOX) {
        float u1 = boxes[t * 4 + 0];
        float v1 = boxes[t * 4 + 1];
        float u2 = boxes[t * 4 + 2];
        float v2 = boxes[t * 4 + 3];
        float hw = fabsf((u1 - u2) * 0.5f);
        float hh = fabsf((v1 - v2) * 0.5f);
        int   r  = (int)fmaxf(hw, hh);          // trunc, positive
        sbx[t]  = (int)((u1 + u2) * 0.5f);      // trunc
        sby[t]  = (int)((v1 + v2) * 0.5f);
        sr[t]   = r;
        scol[t] = (hw <= hh) ? 1 : 0;
        float sigma = (float)(2 * r + 1) / 6.0f;
        s2s[t] = 2.0f * sigma * sigma;
    }
    __syncthreads();

    const int i = blockIdx.x * BS + t;
    float sfg = 0.0f, sbg = 0.0f, snp = 0.0f;

    if (i < NPIX) {
        const int y  = i / W_OUT;
        const int x  = i - y * W_OUT;
        const int py = y * 4;      // nearest-downsample source row
        const int px = x * 4;      // nearest-downsample source col

        float acc = 0.0f;
        for (int b = 0; b < NBOX; ++b) {
            const int dx = px - sbx[b];
            const int dy = py - sby[b];
            const int r  = sr[b];
            if (dx > r || dx < -r || dy > r || dy < -r) continue;   // inside test
            const int hl  = r >> 1;          // r//2
            const int hh2 = (r + 1) >> 1;    // ceil(r/2)
            bool band;
            if (scol[b]) {
                // zero columns [x-r, x-hl) and [x+hh2, x+r]  (inside already holds)
                band = (dx < -hl) || (dx >= hh2);
            } else {
                // zero rows [y-r, y-hh2) and [y+hh2, y+r]
                band = (dy < -hh2) || (dy >= hh2);
            }
            if (band) continue;
            const float d2 = (float)(dx * dx + dy * dy);
            const float g  = expf(-d2 / s2s[b]);
            if (g >= EPS64F) acc += g;       // g < eps64 -> treated as 0
        }

        // fg_small -> masks / weights / target
        const float fgs = fminf(fmaxf(acc, 0.0f), 1.0f);   // clip to [0,1]
        const bool  fgb = fgs > 0.5f;
        const float bgm = fgb ? 0.0f : 1.0f;
        const float w   = fgb ? 13.0f : 1.0f;
        const int   tgt = (int)fgs;          // 1 only where saturated to exactly 1.0

        // 2-class focal loss at this pixel
        const float a  = pred[i];            // channel 0
        const float b2 = pred[NPIX + i];     // channel 1
        const float m  = fmaxf(a, b2);
        const float lse = m + logf(expf(a - m) + expf(b2 - m));
        const float logpt = (tgt ? b2 : a) - lse;
        const float pt = expf(logpt);
        const float om = 1.0f - pt;
        const float loss = -0.25f * om * om * logpt * w;

        sfg = loss * fgs;
        sbg = loss * bgm;
        snp = fgs + bgm;                     // num_pixels contribution
    }

    // wave (64-lane) reduction
    for (int o = 32; o > 0; o >>= 1) {
        sfg += __shfl_down(sfg, o);
        sbg += __shfl_down(sbg, o);
        snp += __shfl_down(snp, o);
    }
    __shared__ float rfg[BS / 64], rbg[BS / 64], rnp[BS / 64];
    const int wave = t >> 6, lane = t & 63;
    if (lane == 0) { rfg[wave] = sfg; rbg[wave] = sbg; rnp[wave] = snp; }
    __syncthreads();
    if (t == 0) {
        float a1 = 0.f, a2 = 0.f, a3 = 0.f;
        for (int wv = 0; wv < BS / 64; ++wv) { a1 += rfg[wv]; a2 += rbg[wv]; a3 += rnp[wv]; }
        part[blockIdx.x]          = a1;
        part[NB + blockIdx.x]     = a2;
        part[2 * NB + blockIdx.x] = a3;
    }
}

__global__ __launch_bounds__(256) void segloss_final(
    const float* __restrict__ part, float* __restrict__ out)
{
    const int t = threadIdx.x;
    float sfg = 0.0f, sbg = 0.0f, snp = 0.0f;
    for (int b = t; b < NB; b += 256) {
        sfg += part[b];
        sbg += part[NB + b];
        snp += part[2 * NB + b];
    }
    for (int o = 32; o > 0; o >>= 1) {
        sfg += __shfl_down(sfg, o);
        sbg += __shfl_down(sbg, o);
        snp += __shfl_down(snp, o);
    }
    __shared__ float rfg[4], rbg[4], rnp[4];
    const int wave = t >> 6, lane = t & 63;
    if (lane == 0) { rfg[wave] = sfg; rbg[wave] = sbg; rnp[wave] = snp; }
    __syncthreads();
    if (t == 0) {
        float a1 = 0.f, a2 = 0.f, a3 = 0.f;
        for (int wv = 0; wv < 4; ++wv) { a1 += rfg[wv]; a2 += rbg[wv]; a3 += rnp[wv]; }
        out[0] = (a1 + a2) / a3;     // (fg_loss + bg_loss), WEIGHT = 1
    }
}

extern "C" void kernel_launch(void* const* d_in, const int* in_sizes, int n_in,
                              void* d_out, int out_size, void* d_ws, size_t ws_size,
                              hipStream_t stream) {
    const float* boxes = (const float*)d_in[0];   // gt_boxes2d (128,4)
    // d_in[1] = images (900,1600): only its shape is used by the reference
    const float* pred  = (const float*)d_in[2];   // fg_pred (1,2,225,400)
    float* out  = (float*)d_out;
    float* part = (float*)d_ws;                   // 3*NB floats = 4224 B

    segloss_main<<<NB, BS, 0, stream>>>(boxes, pred, part);
    segloss_final<<<1, 256, 0, stream>>>(part, out);
}

// Round 2
// 14.158 us; speedup vs baseline: 1.8159x; 1.8159x over previous
//
#include <hip/hip_runtime.h>
#include <math.h>

#define H_OUT 225
#define W_OUT 400
#define NPIX (H_OUT * W_OUT)      // 90000
#define NBOX 128
#define TW 16
#define TH 16
#define TX 25                      // ceil(400/16)
#define TY 15                      // ceil(225/16)
#define NBLK (TX * TY)             // 375
#define BS  256

// EPS64 = np.finfo(np.float64).eps
#define EPS64F 2.2204460492503131e-16f

__global__ __launch_bounds__(BS) void segloss_main(
    const float* __restrict__ boxes,   // (128,4) [u1,v1,u2,v2]
    const float* __restrict__ pred,    // (1,2,225,400)
    float* __restrict__ part)          // 3*NBLK partials: [sfg | sbg | snp]
{
    __shared__ unsigned long long smask[2];
    __shared__ int   nsel;
    __shared__ int   sbx[NBOX], sby[NBOX], sr[NBOX], scol[NBOX];
    __shared__ float s2s[NBOX];        // 2*sigma^2

    const int t = threadIdx.x;
    const int tileX = blockIdx.x % TX;
    const int tileY = blockIdx.x / TX;

    const int x = tileX * TW + (t & (TW - 1));
    const int y = tileY * TH + (t >> 4);
    const bool valid = (x < W_OUT) && (y < H_OUT);
    const int i = valid ? (y * W_OUT + x) : 0;

    // prefetch the focal-loss inputs so global latency overlaps the box work
    const float pa = pred[i];
    const float pb = pred[NPIX + i];

    // tile bbox in source (900x1600) coordinates; pixel p samples source 4*p
    const int x0s = tileX * TW * 4, x1s = x0s + (TW - 1) * 4;
    const int y0s = tileY * TH * 4, y1s = y0s + (TH - 1) * 4;

    // ---- Stage A: per-box tile intersection + deterministic compaction ----
    bool keep = false;
    int bx = 0, by = 0, r = 0, col = 0;
    float two_s2 = 0.0f;
    if (t < NBOX) {
        float u1 = boxes[t * 4 + 0];
        float v1 = boxes[t * 4 + 1];
        float u2 = boxes[t * 4 + 2];
        float v2 = boxes[t * 4 + 3];
        float hw = fabsf((u1 - u2) * 0.5f);
        float hh = fabsf((v1 - v2) * 0.5f);
        r   = (int)fmaxf(hw, hh);          // trunc, positive
        bx  = (int)((u1 + u2) * 0.5f);     // trunc
        by  = (int)((v1 + v2) * 0.5f);
        col = (hw <= hh) ? 1 : 0;
        float sigma = (float)(2 * r + 1) / 6.0f;
        two_s2 = 2.0f * sigma * sigma;
        keep = (bx + r >= x0s) && (bx - r <= x1s) &&
               (by + r >= y0s) && (by - r <= y1s);
    }
    unsigned long long m = __ballot(keep);
    if (t < NBOX && (t & 63) == 0) smask[t >> 6] = m;
    __syncthreads();
    if (t < NBOX) {
        const int w = t >> 6, lane = t & 63;
        const unsigned long long lm = smask[w];
        int off = __popcll(lm & ((1ull << lane) - 1ull));
        if (w) off += __popcll(smask[0]);
        if (keep) {
            sbx[off] = bx; sby[off] = by; sr[off] = r;
            scol[off] = col; s2s[off] = two_s2;
        }
        if (t == 0) nsel = __popcll(smask[0]) + __popcll(smask[1]);
    }
    __syncthreads();

    // ---- Stage B: evaluate only surviving boxes ----
    float sfg = 0.0f, sbg = 0.0f, snp = 0.0f;
    if (valid) {
        const int px = x * 4;
        const int py = y * 4;
        float acc = 0.0f;
        const int ns = nsel;
        for (int k = 0; k < ns; ++k) {
            const int dx = px - sbx[k];
            const int dy = py - sby[k];
            const int rr = sr[k];
            if (dx > rr || dx < -rr || dy > rr || dy < -rr) continue;
            const int hl  = rr >> 1;          // r//2
            const int hh2 = (rr + 1) >> 1;    // ceil(r/2)
            bool band;
            if (scol[k]) {
                band = (dx < -hl) || (dx >= hh2);
            } else {
                band = (dy < -hh2) || (dy >= hh2);
            }
            if (band) continue;
            const float d2 = (float)(dx * dx + dy * dy);
            const float g  = expf(-d2 / s2s[k]);     // same arithmetic as R1 (absmax 0)
            if (g >= EPS64F) acc += g;
        }

        const float fgs = fminf(fmaxf(acc, 0.0f), 1.0f);
        const bool  fgb = fgs > 0.5f;
        const float bgm = fgb ? 0.0f : 1.0f;
        const float w   = fgb ? 13.0f : 1.0f;
        const int   tgt = (int)fgs;           // 1 only where saturated to exactly 1.0

        const float mx  = fmaxf(pa, pb);
        const float lse = mx + logf(expf(pa - mx) + expf(pb - mx));
        const float logpt = (tgt ? pb : pa) - lse;
        const float pt = expf(logpt);
        const float om = 1.0f - pt;
        const float loss = -0.25f * om * om * logpt * w;

        sfg = loss * fgs;
        sbg = loss * bgm;
        snp = fgs + bgm;
    }

    // wave reduction + cross-wave via LDS
    for (int o = 32; o > 0; o >>= 1) {
        sfg += __shfl_down(sfg, o);
        sbg += __shfl_down(sbg, o);
        snp += __shfl_down(snp, o);
    }
    __shared__ float rfg[BS / 64], rbg[BS / 64], rnp[BS / 64];
    const int wave = t >> 6, lane = t & 63;
    if (lane == 0) { rfg[wave] = sfg; rbg[wave] = sbg; rnp[wave] = snp; }
    __syncthreads();
    if (t == 0) {
        float a1 = 0.f, a2 = 0.f, a3 = 0.f;
        for (int wv = 0; wv < BS / 64; ++wv) { a1 += rfg[wv]; a2 += rbg[wv]; a3 += rnp[wv]; }
        part[blockIdx.x]            = a1;
        part[NBLK + blockIdx.x]     = a2;
        part[2 * NBLK + blockIdx.x] = a3;
    }
}

__global__ __launch_bounds__(256) void segloss_final(
    const float* __restrict__ part, float* __restrict__ out)
{
    const int t = threadIdx.x;
    float sfg = 0.0f, sbg = 0.0f, snp = 0.0f;
    for (int b = t; b < NBLK; b += 256) {
        sfg += part[b];
        sbg += part[NBLK + b];
        snp += part[2 * NBLK + b];
    }
    for (int o = 32; o > 0; o >>= 1) {
        sfg += __shfl_down(sfg, o);
        sbg += __shfl_down(sbg, o);
        snp += __shfl_down(snp, o);
    }
    __shared__ float rfg[4], rbg[4], rnp[4];
    const int wave = t >> 6, lane = t & 63;
    if (lane == 0) { rfg[wave] = sfg; rbg[wave] = sbg; rnp[wave] = snp; }
    __syncthreads();
    if (t == 0) {
        float a1 = 0.f, a2 = 0.f, a3 = 0.f;
        for (int wv = 0; wv < 4; ++wv) { a1 += rfg[wv]; a2 += rbg[wv]; a3 += rnp[wv]; }
        out[0] = (a1 + a2) / a3;     // (fg_loss + bg_loss), WEIGHT = 1
    }
}

extern "C" void kernel_launch(void* const* d_in, const int* in_sizes, int n_in,
                              void* d_out, int out_size, void* d_ws, size_t ws_size,
                              hipStream_t stream) {
    const float* boxes = (const float*)d_in[0];   // gt_boxes2d (128,4)
    // d_in[1] = images (900,1600): only its shape is used by the reference
    const float* pred  = (const float*)d_in[2];   // fg_pred (1,2,225,400)
    float* out  = (float*)d_out;
    float* part = (float*)d_ws;                   // 3*NBLK floats = 4500 B

    segloss_main<<<NBLK, BS, 0, stream>>>(boxes, pred, part);
    segloss_final<<<1, 256, 0, stream>>>(part, out);
}